// Round 7
// baseline (655.166 us; speedup 1.0000x reference)
//
#include <hip/hip_runtime.h>
#include <cstdint>
#include <cstddef>

typedef float floatx4 __attribute__((ext_vector_type(4)));
typedef short bf16x8 __attribute__((ext_vector_type(8)));

#define MFMA(a, b, c) __builtin_amdgcn_mfma_f32_16x16x32_bf16((a), (b), (c), 0, 0, 0)

__device__ __forceinline__ unsigned short f2bf(float f) {
  union { float f; unsigned int u; } v; v.f = f;
  unsigned int u = v.u;
  unsigned int r = (u + 0x7FFFu + ((u >> 16) & 1u)) >> 16;
  return (unsigned short)r;
}

__device__ __forceinline__ void gload_lds16(const unsigned short* g, unsigned short* s) {
  __builtin_amdgcn_global_load_lds(
      (const __attribute__((address_space(1))) unsigned int*)g,
      (__attribute__((address_space(3))) unsigned int*)s, 16, 0, 0);
}

// ------------------------------------------------------------------
// All 6 weight transposes fused into one launch (src [R,C] fp32 ->
// dst [C,R] bf16 with row stride ldd).  Flat grid of 32x32 tiles.
// ------------------------------------------------------------------
__global__ __launch_bounds__(256) void transpose_all(
    const float* __restrict__ w_mlp_in, const float* __restrict__ wq,
    const float* __restrict__ wk, const float* __restrict__ wv,
    const float* __restrict__ w_mlp_out, const float* __restrict__ w_attn_out,
    unsigned short* __restrict__ wcatT, unsigned short* __restrict__ wcat2T) {
  int id = blockIdx.x;
  const float* src; unsigned short* dst; int C, ldd, bx, by, q;
  if (id < 4096)       { src = w_mlp_in;   dst = wcatT;                        C = 4096; ldd = 1024; q = id;         bx = q & 127; by = q >> 7; }
  else if (id < 5120)  { src = wq;         dst = wcatT + (size_t)4096 * 1024;  C = 1024; ldd = 1024; q = id - 4096;  bx = q & 31;  by = q >> 5; }
  else if (id < 6144)  { src = wk;         dst = wcatT + (size_t)5120 * 1024;  C = 1024; ldd = 1024; q = id - 5120;  bx = q & 31;  by = q >> 5; }
  else if (id < 7168)  { src = wv;         dst = wcatT + (size_t)6144 * 1024;  C = 1024; ldd = 1024; q = id - 6144;  bx = q & 31;  by = q >> 5; }
  else if (id < 11264) { src = w_mlp_out;  dst = wcat2T;                       C = 1024; ldd = 5120; q = id - 7168;  bx = q & 31;  by = q >> 5; }
  else                 { src = w_attn_out; dst = wcat2T + 4096;                C = 1024; ldd = 5120; q = id - 11264; bx = q & 31;  by = q >> 5; }
  __shared__ float tile[32][33];
  int tx = threadIdx.x & 31, ty = threadIdx.x >> 5;
#pragma unroll
  for (int i = 0; i < 4; i++) {
    int r = ty + i * 8;
    tile[r][tx] = src[(size_t)(by * 32 + r) * C + bx * 32 + tx];
  }
  __syncthreads();
#pragma unroll
  for (int i = 0; i < 4; i++) {
    int r = ty + i * 8;
    dst[(size_t)(bx * 32 + r) * ldd + by * 32 + tx] = f2bf(tile[tx][r]);
  }
}

// ------------------------------------------------------------------
// RMSNorm: x [8192,1024] fp32 -> xn bf16.  One block per row.
// ------------------------------------------------------------------
__global__ __launch_bounds__(256) void rmsnorm_kernel(
    const float* __restrict__ x, const float* __restrict__ scale,
    unsigned short* __restrict__ xn) {
  int row = blockIdx.x;
  const float4 v = ((const float4*)(x + (size_t)row * 1024))[threadIdx.x];
  float ss = v.x * v.x + v.y * v.y + v.z * v.z + v.w * v.w;
#pragma unroll
  for (int off = 1; off < 64; off <<= 1) ss += __shfl_xor(ss, off, 64);
  __shared__ float ws4[4];
  if ((threadIdx.x & 63) == 0) ws4[threadIdx.x >> 6] = ss;
  __syncthreads();
  float tot = ws4[0] + ws4[1] + ws4[2] + ws4[3];
  float rs = rsqrtf(tot * (1.0f / 1024.0f) + 1e-6f);
  const float4 sc = ((const float4*)scale)[threadIdx.x];
  uint2 o;
  o.x = (unsigned)f2bf(v.x * rs * sc.x) | ((unsigned)f2bf(v.y * rs * sc.y) << 16);
  o.y = (unsigned)f2bf(v.z * rs * sc.z) | ((unsigned)f2bf(v.w * rs * sc.w) << 16);
  ((uint2*)(xn + (size_t)row * 1024))[threadIdx.x] = o;
}

// ------------------------------------------------------------------
// GEMM: C[M,N] = A[M,K] * BT[N,K]^T (both bf16, K-major).  128x128
// tile, BK=64 as 2 x 32-k sub-buffers, 4 waves x 64x64 (R4 structure).
//
// CONFLICT-FREE LDS LAYOUT: global_load_lds forces LDS dest =
// base + lane*16B, but the per-lane GLOBAL source is free.  Chunks
// (16 rows x 32 shorts) are stored granule-c-major: lane i fetches
// global (row = i&15, kblock = i>>4), so the MFMA frag read for lane
// (l15,quad) -- which needs (row=l15, k=quad*8) = granule l15+16*quad
// = lane -- becomes addr = chunk_base + lane*16B: fully linear, ZERO
// bank conflicts.  The old row-major layout was 8-way conflicted
// (row stride 64B = 16 banks -> l15, l15+2 same bank), costing ~32
// extra cyc per ds_read_b128 (SQ_LDS_BANK_CONFLICT 1.47e7).
//
// XCD swizzle: id%8 -> (M-region, N-region).
// MODE 6 (fused input): col<4096 gelu->cat[row*5120+col];
//   else q*0.125 / k scatter [B,H,S,HD], v -> [B,H,HD,S]
// MODE 7 (fused output): out[row*1024+col]=v+b1[col]+b2[col]+resid
// ------------------------------------------------------------------
template <int MODE>
__global__ __launch_bounds__(256, 2) void gemm_bt(
    const unsigned short* __restrict__ A, const unsigned short* __restrict__ BT,
    int K, void* __restrict__ outp,
    const float* __restrict__ bias1, const float* __restrict__ bias2,
    const float* __restrict__ resid,
    int msplit, int tm, int tn,
    unsigned short* __restrict__ q_out, unsigned short* __restrict__ k_out,
    unsigned short* __restrict__ v_out) {
  __shared__ unsigned short As[2][128 * 32];
  __shared__ unsigned short Bs[2][128 * 32];

  int id = blockIdx.x + gridDim.x * blockIdx.y;
  int xcd = id & 7, j = id >> 3;
  int mh = xcd % msplit, nq = xcd / msplit;
  int by = mh * tm + j / tn;
  int bx = nq * tn + j % tn;
  int m0 = by * 128, n0 = bx * 128;

  int t = threadIdx.x, lane = t & 63, wave = t >> 6;
  int l15 = lane & 15, quad = lane >> 4;
  int wm = (wave & 1) * 64, wn = (wave >> 1) * 64;

  floatx4 acc[4][4] = {};

  // staging: each wave stages 2 chunks of A and 2 of B per sub-buffer
  int lr = lane & 15;          // row within chunk
  int lk = (lane >> 4) * 8;    // k-offset within chunk (granule-c-major)
  int ch0 = wave * 2, ch1 = wave * 2 + 1;
  const unsigned short* gA0 = A + (size_t)(m0 + ch0 * 16 + lr) * K + lk;
  const unsigned short* gA1 = A + (size_t)(m0 + ch1 * 16 + lr) * K + lk;
  const unsigned short* gB0 = BT + (size_t)(n0 + ch0 * 16 + lr) * K + lk;
  const unsigned short* gB1 = BT + (size_t)(n0 + ch1 * 16 + lr) * K + lk;
  unsigned short* sA0[2] = {&As[0][ch0 * 512 + lane * 8], &As[1][ch0 * 512 + lane * 8]};
  unsigned short* sA1[2] = {&As[0][ch1 * 512 + lane * 8], &As[1][ch1 * 512 + lane * 8]};
  unsigned short* sB0[2] = {&Bs[0][ch0 * 512 + lane * 8], &Bs[1][ch0 * 512 + lane * 8]};
  unsigned short* sB1[2] = {&Bs[0][ch1 * 512 + lane * 8], &Bs[1][ch1 * 512 + lane * 8]};

  int ca = (wm >> 4);  // A chunk base for this wave's frag reads
  int cb = (wn >> 4);

  for (int kt = 0; kt < K; kt += 64) {
    __syncthreads();
#pragma unroll
    for (int kk = 0; kk < 2; kk++) {
      int kg = kt + kk * 32;
      gload_lds16(gA0 + kg, sA0[kk]);
      gload_lds16(gA1 + kg, sA1[kk]);
      gload_lds16(gB0 + kg, sB0[kk]);
      gload_lds16(gB1 + kg, sB1[kk]);
    }
    __syncthreads();
#pragma unroll
    for (int kk = 0; kk < 2; kk++) {
      bf16x8 a[4], b[4];
#pragma unroll
      for (int im = 0; im < 4; im++)
        a[im] = *(const bf16x8*)&As[kk][(ca + im) * 512 + lane * 8];
#pragma unroll
      for (int in_ = 0; in_ < 4; in_++)
        b[in_] = *(const bf16x8*)&Bs[kk][(cb + in_) * 512 + lane * 8];
#pragma unroll
      for (int im = 0; im < 4; im++)
#pragma unroll
        for (int in_ = 0; in_ < 4; in_++)
          acc[im][in_] = MFMA(a[im], b[in_], acc[im][in_]);
    }
  }

#pragma unroll
  for (int im = 0; im < 4; im++) {
#pragma unroll
    for (int in_ = 0; in_ < 4; in_++) {
#pragma unroll
      for (int r = 0; r < 4; r++) {
        int row = m0 + wm + im * 16 + quad * 4 + r;
        int col = n0 + wn + in_ * 16 + l15;
        float v = acc[im][in_][r];
        if constexpr (MODE == 6) {
          if (n0 < 4096) {
            float z = 0.7978845608028654f * (v + 0.044715f * v * v * v);
            float e = __expf(2.0f * z);
            float th = 1.0f - 2.0f / (e + 1.0f);
            ((unsigned short*)outp)[(size_t)row * 5120 + col] = f2bf(0.5f * v * (1.0f + th));
          } else {
            int seg = (n0 - 4096) >> 10;          // 0=q 1=k 2=v (tile-uniform)
            int cs = col - 4096 - (seg << 10);
            int b_ = row >> 11, s = row & 2047, h = cs >> 6, hd = cs & 63;
            if (seg == 0)
              q_out[(((size_t)(b_ * 16 + h)) * 2048 + s) * 64 + hd] = f2bf(v * 0.125f);
            else if (seg == 1)
              k_out[(((size_t)(b_ * 16 + h)) * 2048 + s) * 64 + hd] = f2bf(v);
            else
              v_out[(((size_t)(b_ * 16 + h)) * 64 + hd) * 2048 + s] = f2bf(v);
          }
        } else {
          size_t idx = (size_t)row * 1024 + col;
          ((float*)outp)[idx] = v + bias1[col] + bias2[col] + resid[idx];
        }
      }
    }
  }
}

// ------------------------------------------------------------------
// Flash attention, no-max additive variant (R5 version, unchanged).
// q pre-scaled by 0.125.  q,k [B,H,S,HD]; v [B,H,HD,S] bf16.
// av -> cat cols 4096..5120.  4 waves x 32 q rows; kv tile 64.
// Register prefetch of next K/V tile; Ps via s_waitcnt lgkmcnt(0).
// ------------------------------------------------------------------
__global__ __launch_bounds__(256, 2) void flash_attn(
    const unsigned short* __restrict__ q_buf, const unsigned short* __restrict__ k_buf,
    const unsigned short* __restrict__ v_buf, unsigned short* __restrict__ cat) {
  constexpr int S = 2048, HD = 64;
  constexpr int LK = 72, LV = 72, LP = 68;
  __shared__ unsigned short Ks[64 * LK];
  __shared__ unsigned short Vs[64 * LV];
  __shared__ unsigned short Ps[4][32 * LP];

  int id = blockIdx.x + gridDim.x * blockIdx.y;   // grid (16, 64)
  int xcd = id & 7, j = id >> 3;                  // j in [0,128)
  int bh = xcd * 8 + (j >> 4);
  int qbk = j & 15;

  int t = threadIdx.x, lane = t & 63, wave = t >> 6;
  int l15 = lane & 15, quad = lane >> 4;

  const unsigned short* qp = q_buf + (size_t)bh * S * HD;
  const unsigned short* kp = k_buf + (size_t)bh * S * HD;
  const unsigned short* vp = v_buf + (size_t)bh * HD * S;

  int q0 = qbk * 128 + wave * 32;
  bf16x8 aQ[2][2];
#pragma unroll
  for (int qf = 0; qf < 2; qf++) {
    aQ[qf][0] = *(const bf16x8*)&qp[(size_t)(q0 + qf * 16 + l15) * HD + quad * 8];
    aQ[qf][1] = *(const bf16x8*)&qp[(size_t)(q0 + qf * 16 + l15) * HD + 32 + quad * 8];
  }

  floatx4 acc_o[2][4] = {};
  float lrow[2][4] = {};

  int kr = t >> 3, kc = (t & 7) * 8;

  uint4 rK0 = *(const uint4*)&kp[(size_t)kr * HD + kc];
  uint4 rK1 = *(const uint4*)&kp[(size_t)(kr + 32) * HD + kc];
  uint4 rV0 = *(const uint4*)&vp[(size_t)kr * S + kc];
  uint4 rV1 = *(const uint4*)&vp[(size_t)(kr + 32) * S + kc];

  for (int kv = 0; kv < S; kv += 64) {
    __syncthreads();
    *(uint4*)&Ks[kr * LK + kc] = rK0;
    *(uint4*)&Ks[(kr + 32) * LK + kc] = rK1;
    *(uint4*)&Vs[kr * LV + kc] = rV0;
    *(uint4*)&Vs[(kr + 32) * LV + kc] = rV1;
    __syncthreads();
    if (kv + 64 < S) {
      rK0 = *(const uint4*)&kp[(size_t)(kv + 64 + kr) * HD + kc];
      rK1 = *(const uint4*)&kp[(size_t)(kv + 64 + kr + 32) * HD + kc];
      rV0 = *(const uint4*)&vp[(size_t)kr * S + kv + 64 + kc];
      rV1 = *(const uint4*)&vp[(size_t)(kr + 32) * S + kv + 64 + kc];
    }

    floatx4 z[2][4];
#pragma unroll
    for (int cg = 0; cg < 4; cg++) {
      bf16x8 bk0 = *(const bf16x8*)&Ks[(cg * 16 + l15) * LK + quad * 8];
      bf16x8 bk1 = *(const bf16x8*)&Ks[(cg * 16 + l15) * LK + 32 + quad * 8];
#pragma unroll
      for (int qf = 0; qf < 2; qf++) {
        floatx4 acc = {};
        acc = MFMA(aQ[qf][0], bk0, acc);
        acc = MFMA(aQ[qf][1], bk1, acc);
        z[qf][cg] = acc;
      }
    }
#pragma unroll
    for (int qf = 0; qf < 2; qf++)
#pragma unroll
      for (int cg = 0; cg < 4; cg++)
#pragma unroll
        for (int r = 0; r < 4; r++) {
          float e = __expf(z[qf][cg][r]);
          lrow[qf][r] += e;
          Ps[wave][(qf * 16 + quad * 4 + r) * LP + cg * 16 + l15] = f2bf(e);
        }
    asm volatile("s_waitcnt lgkmcnt(0)" ::: "memory");
#pragma unroll
    for (int c = 0; c < 2; c++) {
      bf16x8 aP[2];
#pragma unroll
      for (int qf = 0; qf < 2; qf++) {
        const unsigned short* pp = &Ps[wave][(qf * 16 + l15) * LP + c * 32 + quad * 8];
        ((uint2*)&aP[qf])[0] = *(const uint2*)pp;
        ((uint2*)&aP[qf])[1] = *(const uint2*)(pp + 4);
      }
#pragma unroll
      for (int n = 0; n < 4; n++) {
        bf16x8 bv = *(const bf16x8*)&Vs[(n * 16 + l15) * LV + c * 32 + quad * 8];
        acc_o[0][n] = MFMA(aP[0], bv, acc_o[0][n]);
        acc_o[1][n] = MFMA(aP[1], bv, acc_o[1][n]);
      }
    }
  }

#pragma unroll
  for (int qf = 0; qf < 2; qf++)
#pragma unroll
    for (int r = 0; r < 4; r++) {
      float s = lrow[qf][r];
#pragma unroll
      for (int off = 1; off < 16; off <<= 1) s += __shfl_xor(s, off, 16);
      lrow[qf][r] = s;
    }

  int b_ = bh >> 4, h = bh & 15;
#pragma unroll
  for (int qf = 0; qf < 2; qf++)
#pragma unroll
    for (int r = 0; r < 4; r++) {
      float inv = 1.0f / lrow[qf][r];
      int srow = q0 + qf * 16 + quad * 4 + r;
      size_t base = ((size_t)(b_ * 2048 + srow)) * 5120 + 4096 + h * 64;
#pragma unroll
      for (int n = 0; n < 4; n++)
        cat[base + n * 16 + l15] = f2bf(acc_o[qf][n][r] * inv);
    }
}

// ------------------------------------------------------------------
extern "C" void kernel_launch(void* const* d_in, const int* in_sizes, int n_in,
                              void* d_out, int out_size, void* d_ws, size_t ws_size,
                              hipStream_t stream) {
  (void)in_sizes; (void)n_in; (void)out_size; (void)ws_size;
  const float* x          = (const float*)d_in[0];
  const float* pns        = (const float*)d_in[1];
  const float* w_mlp_in   = (const float*)d_in[2];
  const float* wq         = (const float*)d_in[3];
  const float* wk         = (const float*)d_in[4];
  const float* wv         = (const float*)d_in[5];
  const float* w_mlp_out  = (const float*)d_in[6];
  const float* b_mlp_out  = (const float*)d_in[7];
  const float* w_attn_out = (const float*)d_in[8];
  const float* b_attn_out = (const float*)d_in[9];
  float* out = (float*)d_out;

  char* ws = (char*)d_ws;
  size_t off = 0;
  auto alloc = [&](size_t bytes) {
    void* p = ws + off;
    off += (bytes + 255) & ~(size_t)255;
    return p;
  };
  const size_t M = 8192;
  unsigned short* xn     = (unsigned short*)alloc(M * 1024 * 2);
  unsigned short* wcatT  = (unsigned short*)alloc((size_t)7168 * 1024 * 2);  // [mlp_in|q|k|v][N,K]
  unsigned short* wcat2T = (unsigned short*)alloc((size_t)1024 * 5120 * 2);  // [N=1024, K=5120]
  unsigned short* cat    = (unsigned short*)alloc(M * 5120 * 2);             // [h | av]
  unsigned short* qb     = (unsigned short*)alloc(M * 1024 * 2);
  unsigned short* kb     = (unsigned short*)alloc(M * 1024 * 2);
  unsigned short* vb     = (unsigned short*)alloc(M * 1024 * 2);

  transpose_all<<<dim3(12288), 256, 0, stream>>>(
      w_mlp_in, wq, wk, wv, w_mlp_out, w_attn_out, wcatT, wcat2T);

  rmsnorm_kernel<<<dim3(8192), 256, 0, stream>>>(x, pns, xn);

  // fused input GEMM: [8192,1024] x [7168,1024]^T; 128x128 tiles,
  // grid 56x64 = 3584 blocks; msplit=2 nsplit=4 (tn=14)
  gemm_bt<6><<<dim3(56, 64), 256, 0, stream>>>(
      xn, wcatT, 1024, cat, nullptr, nullptr, nullptr, 2, 32, 14, qb, kb, vb);

  flash_attn<<<dim3(16, 64), 256, 0, stream>>>(qb, kb, vb, cat);

  // fused output GEMM: [8192,5120] x [1024,5120]^T; 128x128 tiles,
  // grid 8x64 = 512 blocks; msplit=2 nsplit=4 (tn=2)
  gemm_bt<7><<<dim3(8, 64), 256, 0, stream>>>(
      cat, wcat2T, 5120, out, b_mlp_out, b_attn_out, x, 2, 32, 2, nullptr, nullptr, nullptr);
}

// Round 8
// 547.843 us; speedup vs baseline: 1.1959x; 1.1959x over previous
//
#include <hip/hip_runtime.h>
#include <cstdint>
#include <cstddef>

typedef float floatx4 __attribute__((ext_vector_type(4)));
typedef short bf16x8 __attribute__((ext_vector_type(8)));

#define MFMA(a, b, c) __builtin_amdgcn_mfma_f32_16x16x32_bf16((a), (b), (c), 0, 0, 0)

__device__ __forceinline__ unsigned short f2bf(float f) {
  union { float f; unsigned int u; } v; v.f = f;
  unsigned int u = v.u;
  unsigned int r = (u + 0x7FFFu + ((u >> 16) & 1u)) >> 16;
  return (unsigned short)r;
}

__device__ __forceinline__ void gload_lds16(const unsigned short* g, unsigned short* s) {
  __builtin_amdgcn_global_load_lds(
      (const __attribute__((address_space(1))) unsigned int*)g,
      (__attribute__((address_space(3))) unsigned int*)s, 16, 0, 0);
}

// ------------------------------------------------------------------
// All 6 weight transposes fused into one launch (src [R,C] fp32 ->
// dst [C,R] bf16 with row stride ldd).  Flat grid of 32x32 tiles.
// ------------------------------------------------------------------
__global__ __launch_bounds__(256) void transpose_all(
    const float* __restrict__ w_mlp_in, const float* __restrict__ wq,
    const float* __restrict__ wk, const float* __restrict__ wv,
    const float* __restrict__ w_mlp_out, const float* __restrict__ w_attn_out,
    unsigned short* __restrict__ wcatT, unsigned short* __restrict__ wcat2T) {
  int id = blockIdx.x;
  const float* src; unsigned short* dst; int C, ldd, bx, by, q;
  if (id < 4096)       { src = w_mlp_in;   dst = wcatT;                        C = 4096; ldd = 1024; q = id;         bx = q & 127; by = q >> 7; }
  else if (id < 5120)  { src = wq;         dst = wcatT + (size_t)4096 * 1024;  C = 1024; ldd = 1024; q = id - 4096;  bx = q & 31;  by = q >> 5; }
  else if (id < 6144)  { src = wk;         dst = wcatT + (size_t)5120 * 1024;  C = 1024; ldd = 1024; q = id - 5120;  bx = q & 31;  by = q >> 5; }
  else if (id < 7168)  { src = wv;         dst = wcatT + (size_t)6144 * 1024;  C = 1024; ldd = 1024; q = id - 6144;  bx = q & 31;  by = q >> 5; }
  else if (id < 11264) { src = w_mlp_out;  dst = wcat2T;                       C = 1024; ldd = 5120; q = id - 7168;  bx = q & 31;  by = q >> 5; }
  else                 { src = w_attn_out; dst = wcat2T + 4096;                C = 1024; ldd = 5120; q = id - 11264; bx = q & 31;  by = q >> 5; }
  __shared__ float tile[32][33];
  int tx = threadIdx.x & 31, ty = threadIdx.x >> 5;
#pragma unroll
  for (int i = 0; i < 4; i++) {
    int r = ty + i * 8;
    tile[r][tx] = src[(size_t)(by * 32 + r) * C + bx * 32 + tx];
  }
  __syncthreads();
#pragma unroll
  for (int i = 0; i < 4; i++) {
    int r = ty + i * 8;
    dst[(size_t)(bx * 32 + r) * ldd + by * 32 + tx] = f2bf(tile[tx][r]);
  }
}

// ------------------------------------------------------------------
// RMSNorm: x [8192,1024] fp32 -> xn bf16.  One block per row.
// ------------------------------------------------------------------
__global__ __launch_bounds__(256) void rmsnorm_kernel(
    const float* __restrict__ x, const float* __restrict__ scale,
    unsigned short* __restrict__ xn) {
  int row = blockIdx.x;
  const float4 v = ((const float4*)(x + (size_t)row * 1024))[threadIdx.x];
  float ss = v.x * v.x + v.y * v.y + v.z * v.z + v.w * v.w;
#pragma unroll
  for (int off = 1; off < 64; off <<= 1) ss += __shfl_xor(ss, off, 64);
  __shared__ float ws4[4];
  if ((threadIdx.x & 63) == 0) ws4[threadIdx.x >> 6] = ss;
  __syncthreads();
  float tot = ws4[0] + ws4[1] + ws4[2] + ws4[3];
  float rs = rsqrtf(tot * (1.0f / 1024.0f) + 1e-6f);
  const float4 sc = ((const float4*)scale)[threadIdx.x];
  uint2 o;
  o.x = (unsigned)f2bf(v.x * rs * sc.x) | ((unsigned)f2bf(v.y * rs * sc.y) << 16);
  o.y = (unsigned)f2bf(v.z * rs * sc.z) | ((unsigned)f2bf(v.w * rs * sc.w) << 16);
  ((uint2*)(xn + (size_t)row * 1024))[threadIdx.x] = o;
}

// ------------------------------------------------------------------
// GEMM: C[M,N] = A[M,K] * BT[N,K]^T (both bf16, K-major).  128x128
// tile, BK=64 as 2 x 32-k sub-buffers, 4 waves x 64x64 (R4 structure).
//
// HYBRID SWIZZLE (coalesced staging + conflict-free frag reads):
// global_load_lds forces LDS dest = base + lane*16B; the free knob is
// the lane->global map.  Lane L fetches (row = L>>2,
// granule = (L&3) ^ ((L>>3)&3)): each aligned 4-lane group covers one
// contiguous 64B global line (granules permuted within the line) ->
// R4-grade coalescing.  Inverse map: frag granule (row=l15, g=quad)
// sits at lane pos 4*l15 + (quad ^ ((l15>>1)&3)); per aligned 8-lane
// frag group these positions mod 8 form a full permutation -> ZERO
// ds_read_b128 bank conflicts (R4's row-major was 8-way: 1.47e7
// conflict-cycles ~ 2.8x LDS-pipe inflation; R7's conflict-free
// variant broke coalescing instead, FETCH +35%).
//
// XCD swizzle: id%8 -> (M-region, N-region).
// MODE 6 (fused input): col<4096 gelu->cat[row*5120+col];
//   else q*0.125 / k scatter [B,H,S,HD], v -> [B,H,HD,S]
// MODE 7 (fused output): out[row*1024+col]=v+b1[col]+b2[col]+resid
// ------------------------------------------------------------------
template <int MODE>
__global__ __launch_bounds__(256, 2) void gemm_bt(
    const unsigned short* __restrict__ A, const unsigned short* __restrict__ BT,
    int K, void* __restrict__ outp,
    const float* __restrict__ bias1, const float* __restrict__ bias2,
    const float* __restrict__ resid,
    int msplit, int tm, int tn,
    unsigned short* __restrict__ q_out, unsigned short* __restrict__ k_out,
    unsigned short* __restrict__ v_out) {
  __shared__ unsigned short As[2][128 * 32];
  __shared__ unsigned short Bs[2][128 * 32];

  int id = blockIdx.x + gridDim.x * blockIdx.y;
  int xcd = id & 7, j = id >> 3;
  int mh = xcd % msplit, nq = xcd / msplit;
  int by = mh * tm + j / tn;
  int bx = nq * tn + j % tn;
  int m0 = by * 128, n0 = bx * 128;

  int t = threadIdx.x, lane = t & 63, wave = t >> 6;
  int l15 = lane & 15, quad = lane >> 4;
  int wm = (wave & 1) * 64, wn = (wave >> 1) * 64;

  floatx4 acc[4][4] = {};

  // staging: lane L -> global (row L>>2, granule (L&3)^((L>>3)&3))
  int lr = lane >> 2;                        // row 0..15 within chunk
  int lg = (lane & 3) ^ ((lane >> 3) & 3);   // 16B granule within row
  int ch0 = wave * 2, ch1 = wave * 2 + 1;
  const unsigned short* gA0 = A + (size_t)(m0 + ch0 * 16 + lr) * K + lg * 8;
  const unsigned short* gA1 = A + (size_t)(m0 + ch1 * 16 + lr) * K + lg * 8;
  const unsigned short* gB0 = BT + (size_t)(n0 + ch0 * 16 + lr) * K + lg * 8;
  const unsigned short* gB1 = BT + (size_t)(n0 + ch1 * 16 + lr) * K + lg * 8;
  unsigned short* sA0[2] = {&As[0][ch0 * 512 + lane * 8], &As[1][ch0 * 512 + lane * 8]};
  unsigned short* sA1[2] = {&As[0][ch1 * 512 + lane * 8], &As[1][ch1 * 512 + lane * 8]};
  unsigned short* sB0[2] = {&Bs[0][ch0 * 512 + lane * 8], &Bs[1][ch0 * 512 + lane * 8]};
  unsigned short* sB1[2] = {&Bs[0][ch1 * 512 + lane * 8], &Bs[1][ch1 * 512 + lane * 8]};

  // frag read: inverse map, conflict-free (see header comment)
  int fo = (4 * l15 + (quad ^ ((l15 >> 1) & 3))) * 8;
  int ca = (wm >> 4);  // chunk base of this wave's A rows
  int cb = (wn >> 4);

  for (int kt = 0; kt < K; kt += 64) {
    __syncthreads();
#pragma unroll
    for (int kk = 0; kk < 2; kk++) {
      int kg = kt + kk * 32;
      gload_lds16(gA0 + kg, sA0[kk]);
      gload_lds16(gA1 + kg, sA1[kk]);
      gload_lds16(gB0 + kg, sB0[kk]);
      gload_lds16(gB1 + kg, sB1[kk]);
    }
    __syncthreads();
#pragma unroll
    for (int kk = 0; kk < 2; kk++) {
      bf16x8 a[4], b[4];
#pragma unroll
      for (int im = 0; im < 4; im++)
        a[im] = *(const bf16x8*)&As[kk][(ca + im) * 512 + fo];
#pragma unroll
      for (int in_ = 0; in_ < 4; in_++)
        b[in_] = *(const bf16x8*)&Bs[kk][(cb + in_) * 512 + fo];
#pragma unroll
      for (int im = 0; im < 4; im++)
#pragma unroll
        for (int in_ = 0; in_ < 4; in_++)
          acc[im][in_] = MFMA(a[im], b[in_], acc[im][in_]);
    }
  }

#pragma unroll
  for (int im = 0; im < 4; im++) {
#pragma unroll
    for (int in_ = 0; in_ < 4; in_++) {
#pragma unroll
      for (int r = 0; r < 4; r++) {
        int row = m0 + wm + im * 16 + quad * 4 + r;
        int col = n0 + wn + in_ * 16 + l15;
        float v = acc[im][in_][r];
        if constexpr (MODE == 6) {
          if (n0 < 4096) {
            float z = 0.7978845608028654f * (v + 0.044715f * v * v * v);
            float e = __expf(2.0f * z);
            float th = 1.0f - 2.0f / (e + 1.0f);
            ((unsigned short*)outp)[(size_t)row * 5120 + col] = f2bf(0.5f * v * (1.0f + th));
          } else {
            int seg = (n0 - 4096) >> 10;          // 0=q 1=k 2=v (tile-uniform)
            int cs = col - 4096 - (seg << 10);
            int b_ = row >> 11, s = row & 2047, h = cs >> 6, hd = cs & 63;
            if (seg == 0)
              q_out[(((size_t)(b_ * 16 + h)) * 2048 + s) * 64 + hd] = f2bf(v * 0.125f);
            else if (seg == 1)
              k_out[(((size_t)(b_ * 16 + h)) * 2048 + s) * 64 + hd] = f2bf(v);
            else
              v_out[(((size_t)(b_ * 16 + h)) * 64 + hd) * 2048 + s] = f2bf(v);
          }
        } else {
          size_t idx = (size_t)row * 1024 + col;
          ((float*)outp)[idx] = v + bias1[col] + bias2[col] + resid[idx];
        }
      }
    }
  }
}

// ------------------------------------------------------------------
// Flash attention, no-max additive variant (R5 version, unchanged).
// q pre-scaled by 0.125.  q,k [B,H,S,HD]; v [B,H,HD,S] bf16.
// av -> cat cols 4096..5120.  4 waves x 32 q rows; kv tile 64.
// Register prefetch of next K/V tile; Ps via s_waitcnt lgkmcnt(0).
// ------------------------------------------------------------------
__global__ __launch_bounds__(256, 2) void flash_attn(
    const unsigned short* __restrict__ q_buf, const unsigned short* __restrict__ k_buf,
    const unsigned short* __restrict__ v_buf, unsigned short* __restrict__ cat) {
  constexpr int S = 2048, HD = 64;
  constexpr int LK = 72, LV = 72, LP = 68;
  __shared__ unsigned short Ks[64 * LK];
  __shared__ unsigned short Vs[64 * LV];
  __shared__ unsigned short Ps[4][32 * LP];

  int id = blockIdx.x + gridDim.x * blockIdx.y;   // grid (16, 64)
  int xcd = id & 7, j = id >> 3;                  // j in [0,128)
  int bh = xcd * 8 + (j >> 4);
  int qbk = j & 15;

  int t = threadIdx.x, lane = t & 63, wave = t >> 6;
  int l15 = lane & 15, quad = lane >> 4;

  const unsigned short* qp = q_buf + (size_t)bh * S * HD;
  const unsigned short* kp = k_buf + (size_t)bh * S * HD;
  const unsigned short* vp = v_buf + (size_t)bh * HD * S;

  int q0 = qbk * 128 + wave * 32;
  bf16x8 aQ[2][2];
#pragma unroll
  for (int qf = 0; qf < 2; qf++) {
    aQ[qf][0] = *(const bf16x8*)&qp[(size_t)(q0 + qf * 16 + l15) * HD + quad * 8];
    aQ[qf][1] = *(const bf16x8*)&qp[(size_t)(q0 + qf * 16 + l15) * HD + 32 + quad * 8];
  }

  floatx4 acc_o[2][4] = {};
  float lrow[2][4] = {};

  int kr = t >> 3, kc = (t & 7) * 8;

  uint4 rK0 = *(const uint4*)&kp[(size_t)kr * HD + kc];
  uint4 rK1 = *(const uint4*)&kp[(size_t)(kr + 32) * HD + kc];
  uint4 rV0 = *(const uint4*)&vp[(size_t)kr * S + kc];
  uint4 rV1 = *(const uint4*)&vp[(size_t)(kr + 32) * S + kc];

  for (int kv = 0; kv < S; kv += 64) {
    __syncthreads();
    *(uint4*)&Ks[kr * LK + kc] = rK0;
    *(uint4*)&Ks[(kr + 32) * LK + kc] = rK1;
    *(uint4*)&Vs[kr * LV + kc] = rV0;
    *(uint4*)&Vs[(kr + 32) * LV + kc] = rV1;
    __syncthreads();
    if (kv + 64 < S) {
      rK0 = *(const uint4*)&kp[(size_t)(kv + 64 + kr) * HD + kc];
      rK1 = *(const uint4*)&kp[(size_t)(kv + 64 + kr + 32) * HD + kc];
      rV0 = *(const uint4*)&vp[(size_t)kr * S + kv + 64 + kc];
      rV1 = *(const uint4*)&vp[(size_t)(kr + 32) * S + kv + 64 + kc];
    }

    floatx4 z[2][4];
#pragma unroll
    for (int cg = 0; cg < 4; cg++) {
      bf16x8 bk0 = *(const bf16x8*)&Ks[(cg * 16 + l15) * LK + quad * 8];
      bf16x8 bk1 = *(const bf16x8*)&Ks[(cg * 16 + l15) * LK + 32 + quad * 8];
#pragma unroll
      for (int qf = 0; qf < 2; qf++) {
        floatx4 acc = {};
        acc = MFMA(aQ[qf][0], bk0, acc);
        acc = MFMA(aQ[qf][1], bk1, acc);
        z[qf][cg] = acc;
      }
    }
#pragma unroll
    for (int qf = 0; qf < 2; qf++)
#pragma unroll
      for (int cg = 0; cg < 4; cg++)
#pragma unroll
        for (int r = 0; r < 4; r++) {
          float e = __expf(z[qf][cg][r]);
          lrow[qf][r] += e;
          Ps[wave][(qf * 16 + quad * 4 + r) * LP + cg * 16 + l15] = f2bf(e);
        }
    asm volatile("s_waitcnt lgkmcnt(0)" ::: "memory");
#pragma unroll
    for (int c = 0; c < 2; c++) {
      bf16x8 aP[2];
#pragma unroll
      for (int qf = 0; qf < 2; qf++) {
        const unsigned short* pp = &Ps[wave][(qf * 16 + l15) * LP + c * 32 + quad * 8];
        ((uint2*)&aP[qf])[0] = *(const uint2*)pp;
        ((uint2*)&aP[qf])[1] = *(const uint2*)(pp + 4);
      }
#pragma unroll
      for (int n = 0; n < 4; n++) {
        bf16x8 bv = *(const bf16x8*)&Vs[(n * 16 + l15) * LV + c * 32 + quad * 8];
        acc_o[0][n] = MFMA(aP[0], bv, acc_o[0][n]);
        acc_o[1][n] = MFMA(aP[1], bv, acc_o[1][n]);
      }
    }
  }

#pragma unroll
  for (int qf = 0; qf < 2; qf++)
#pragma unroll
    for (int r = 0; r < 4; r++) {
      float s = lrow[qf][r];
#pragma unroll
      for (int off = 1; off < 16; off <<= 1) s += __shfl_xor(s, off, 16);
      lrow[qf][r] = s;
    }

  int b_ = bh >> 4, h = bh & 15;
#pragma unroll
  for (int qf = 0; qf < 2; qf++)
#pragma unroll
    for (int r = 0; r < 4; r++) {
      float inv = 1.0f / lrow[qf][r];
      int srow = q0 + qf * 16 + quad * 4 + r;
      size_t base = ((size_t)(b_ * 2048 + srow)) * 5120 + 4096 + h * 64;
#pragma unroll
      for (int n = 0; n < 4; n++)
        cat[base + n * 16 + l15] = f2bf(acc_o[qf][n][r] * inv);
    }
}

// ------------------------------------------------------------------
extern "C" void kernel_launch(void* const* d_in, const int* in_sizes, int n_in,
                              void* d_out, int out_size, void* d_ws, size_t ws_size,
                              hipStream_t stream) {
  (void)in_sizes; (void)n_in; (void)out_size; (void)ws_size;
  const float* x          = (const float*)d_in[0];
  const float* pns        = (const float*)d_in[1];
  const float* w_mlp_in   = (const float*)d_in[2];
  const float* wq         = (const float*)d_in[3];
  const float* wk         = (const float*)d_in[4];
  const float* wv         = (const float*)d_in[5];
  const float* w_mlp_out  = (const float*)d_in[6];
  const float* b_mlp_out  = (const float*)d_in[7];
  const float* w_attn_out = (const float*)d_in[8];
  const float* b_attn_out = (const float*)d_in[9];
  float* out = (float*)d_out;

  char* ws = (char*)d_ws;
  size_t off = 0;
  auto alloc = [&](size_t bytes) {
    void* p = ws + off;
    off += (bytes + 255) & ~(size_t)255;
    return p;
  };
  const size_t M = 8192;
  unsigned short* xn     = (unsigned short*)alloc(M * 1024 * 2);
  unsigned short* wcatT  = (unsigned short*)alloc((size_t)7168 * 1024 * 2);  // [mlp_in|q|k|v][N,K]
  unsigned short* wcat2T = (unsigned short*)alloc((size_t)1024 * 5120 * 2);  // [N=1024, K=5120]
  unsigned short* cat    = (unsigned short*)alloc(M * 5120 * 2);             // [h | av]
  unsigned short* qb     = (unsigned short*)alloc(M * 1024 * 2);
  unsigned short* kb     = (unsigned short*)alloc(M * 1024 * 2);
  unsigned short* vb     = (unsigned short*)alloc(M * 1024 * 2);

  transpose_all<<<dim3(12288), 256, 0, stream>>>(
      w_mlp_in, wq, wk, wv, w_mlp_out, w_attn_out, wcatT, wcat2T);

  rmsnorm_kernel<<<dim3(8192), 256, 0, stream>>>(x, pns, xn);

  // fused input GEMM: [8192,1024] x [7168,1024]^T; 128x128 tiles,
  // grid 56x64 = 3584 blocks; msplit=2 nsplit=4 (tn=14)
  gemm_bt<6><<<dim3(56, 64), 256, 0, stream>>>(
      xn, wcatT, 1024, cat, nullptr, nullptr, nullptr, 2, 32, 14, qb, kb, vb);

  flash_attn<<<dim3(16, 64), 256, 0, stream>>>(qb, kb, vb, cat);

  // fused output GEMM: [8192,5120] x [1024,5120]^T; 128x128 tiles,
  // grid 8x64 = 512 blocks; msplit=2 nsplit=4 (tn=2)
  gemm_bt<7><<<dim3(8, 64), 256, 0, stream>>>(
      cat, wcat2T, 5120, out, b_mlp_out, b_attn_out, x, 2, 32, 2, nullptr, nullptr, nullptr);
}